// Round 1
// baseline (199.929 us; speedup 1.0000x reference)
//
#include <hip/hip_runtime.h>
#include <hip/hip_bf16.h>

// Problem constants: b=8, lq=lk=2048, d=256
#define BB 8
#define LQ 2048
#define LK 2048
#define DD 256
#define OUT0_N (BB*LQ*DD)      // 4194304 elements (LN output), attn follows

typedef short s16x8 __attribute__((ext_vector_type(8)));
typedef float f32x4 __attribute__((ext_vector_type(4)));

__device__ __forceinline__ unsigned short f2b(float x){
  unsigned int u = __float_as_uint(x);
  u += 0x7fffu + ((u >> 16) & 1u);           // RNE
  return (unsigned short)(u >> 16);
}
__device__ __forceinline__ float b2f(unsigned short h){
  return __uint_as_float(((unsigned int)h) << 16);
}
// flagged scalar load: bf=1 -> buffer holds bf16, else f32
__device__ __forceinline__ float ldf(const void* p, long i, int bf){
  return bf ? b2f(((const unsigned short*)p)[i]) : ((const float*)p)[i];
}
// flagged 8-wide load, returns 8 bf16 (MFMA fragment). i must be multiple of 8.
__device__ __forceinline__ s16x8 ld8(const void* p, long i, int bf){
  if (bf) return *(const s16x8*)((const unsigned short*)p + i);
  const float* f = (const float*)p + i;
  float4 a = *(const float4*)(f);
  float4 c = *(const float4*)(f + 4);
  s16x8 r;
  r[0]=(short)f2b(a.x); r[1]=(short)f2b(a.y); r[2]=(short)f2b(a.z); r[3]=(short)f2b(a.w);
  r[4]=(short)f2b(c.x); r[5]=(short)f2b(c.y); r[6]=(short)f2b(c.z); r[7]=(short)f2b(c.w);
  return r;
}
__device__ __forceinline__ float wmax(float v){
  #pragma unroll
  for (int o=32;o;o>>=1) v = fmaxf(v, __shfl_xor(v, o, 64));
  return v;
}
__device__ __forceinline__ float wsum(float v){
  #pragma unroll
  for (int o=32;o;o>>=1) v += __shfl_xor(v, o, 64);
  return v;
}

// ---------------- K0: runtime dtype detection ----------------
// flags[0]=1 -> mask stored as 1-byte bools (else int32 0/1)
// flags[1]=1 -> float tensors stored as bf16 (else f32)
__global__ void k_detect(const void* q, const void* mask, int* flags){
  __shared__ int sb, sc;
  if (threadIdx.x == 0){ sb = 0; sc = 0; }
  __syncthreads();
  const unsigned int* mw = (const unsigned int*)mask;
  int any = 0;
  for (int i = threadIdx.x; i < 1024; i += 256) if (mw[i] > 1u) any = 1;
  if (any) atomicOr(&sb, 1);
  // f32 normals reinterpret in-range; packed bf16 pairs reinterpret to 2^~120+ magnitudes
  float x = fabsf(((const float*)q)[threadIdx.x]);
  if (x > 1e-6f && x < 100.0f) atomicAdd(&sc, 1);
  __syncthreads();
  if (threadIdx.x == 0){
    flags[0] = sb;
    flags[1] = (sc < 192) ? 1 : 0;
  }
}

// ---------------- K1: sk[b,j] = dot(k[b,j,:], w_k) ----------------
// one wave per row, 4 elems/lane
__global__ __launch_bounds__(256) void k_sk(const void* kk, const void* sh,
                                            float* sk, const int* flags){
  int bf = flags[1];
  int wid  = (blockIdx.x << 2) + (threadIdx.x >> 6);   // row 0..16383
  int lane = threadIdx.x & 63;
  long base = (long)wid * DD + lane * 4;
  float acc = 0.f;
  #pragma unroll
  for (int c = 0; c < 4; ++c)
    acc += ldf(kk, base + c, bf) * ldf(sh, DD + lane*4 + c, bf);
  acc = wsum(acc);
  if (lane == 0) sk[wid] = acc;
}

// ---------------- K1b: vt[b][d][j] = sum_e fc_w[d][e] * v[b,j,e]  (bf16) ----------------
// MFMA: A = fc_w (M=d, K=e contiguous), B = v^T (N=j, lane loads v[j][e..e+8] contiguous)
__global__ __launch_bounds__(256) void k_vt(const void* v, const void* fc,
                                            unsigned short* vt, const int* flags){
  int bf = flags[1];
  int wid  = (blockIdx.x << 2) + (threadIdx.x >> 6);   // 0..4095
  int lane = threadIdx.x & 63;
  int dbase = (wid & 15) << 4;     // 16 d per wave
  int jbase = (wid >> 4) << 6;     // 64 j per wave (stays within one batch)
  int r = lane & 15, g = lane >> 4;
  f32x4 acc[4];
  #pragma unroll
  for (int t2=0;t2<4;t2++) acc[t2] = (f32x4){0.f,0.f,0.f,0.f};
  #pragma unroll
  for (int ks = 0; ks < 8; ++ks){
    int k0 = ks*32 + g*8;
    s16x8 a = ld8(fc, (long)(dbase + r)*DD + k0, bf);
    #pragma unroll
    for (int t2 = 0; t2 < 4; ++t2){
      s16x8 bq = ld8(v, (long)(jbase + t2*16 + r)*DD + k0, bf);
      acc[t2] = __builtin_amdgcn_mfma_f32_16x16x32_bf16(a, bq, acc[t2], 0, 0, 0);
    }
  }
  int bidx = jbase >> 11;
  int jj   = jbase & 2047;
  long vb  = (long)bidx * DD * LK;
  #pragma unroll
  for (int t2 = 0; t2 < 4; ++t2){
    #pragma unroll
    for (int reg = 0; reg < 4; ++reg){
      int d = dbase + g*4 + reg;      // C/D: row = (lane>>4)*4+reg
      int j = jj + t2*16 + r;         // C/D: col = lane&15
      vt[vb + (long)d*LK + j] = f2b(acc[t2][reg]);
    }
  }
}

// ---------------- K2: masked softmax, writes attn to d_out ----------------
// sq cancels: p = exp(sk_j - m)/s over unmasked j; all-masked row -> uniform 1/2048
__global__ __launch_bounds__(256) void k_sm(const void* mask, const float* sk,
                                            void* d_out, const int* flags){
  __shared__ float sks[LK];
  int mbytes = flags[0], bf = flags[1];
  int b    = blockIdx.x >> 7;
  int tile = blockIdx.x & 127;     // 16 rows per block
  int t = threadIdx.x, lane = t & 63, w = t >> 6;
  const float* skb = sk + b * LK;
  #pragma unroll
  for (int i = 0; i < 8; ++i) sks[t + 256*i] = skb[t + 256*i];
  __syncthreads();
  for (int rr = 0; rr < 4; ++rr){
    int i = tile*16 + w*4 + rr;
    long rowm = ((long)b*LQ + i) * (long)LK;   // element index of row start
    unsigned int mreg[8];
    float4 sv[8];
    float m = -3.0e38f;
    #pragma unroll
    for (int g = 0; g < 8; ++g){
      int j0 = (g*64 + lane) * 4;
      unsigned int mr;
      if (mbytes){
        mr = *(const unsigned int*)((const unsigned char*)mask + rowm + j0);
      } else {
        int4 m4 = *(const int4*)((const int*)mask + rowm + j0);
        mr = (m4.x?1u:0u) | ((m4.y?1u:0u)<<8) | ((m4.z?1u:0u)<<16) | ((m4.w?1u:0u)<<24);
      }
      mreg[g] = mr;
      float4 s4 = *(const float4*)(&sks[j0]);
      sv[g] = s4;
      if (!(mr & 0x000000ffu)) m = fmaxf(m, s4.x);
      if (!(mr & 0x0000ff00u)) m = fmaxf(m, s4.y);
      if (!(mr & 0x00ff0000u)) m = fmaxf(m, s4.z);
      if (!(mr & 0xff000000u)) m = fmaxf(m, s4.w);
    }
    m = wmax(m);
    bool allm = (m < -1.0e37f);
    float ssum = 0.f;
    #pragma unroll
    for (int g = 0; g < 8; ++g){
      unsigned int mr = mreg[g];
      float4 e;
      e.x = (mr & 0x000000ffu) ? 0.f : __expf(sv[g].x - m);
      e.y = (mr & 0x0000ff00u) ? 0.f : __expf(sv[g].y - m);
      e.z = (mr & 0x00ff0000u) ? 0.f : __expf(sv[g].z - m);
      e.w = (mr & 0xff000000u) ? 0.f : __expf(sv[g].w - m);
      sv[g] = e;
      ssum += e.x + e.y + e.z + e.w;
    }
    ssum = wsum(ssum);
    float inv = allm ? (1.0f/2048.0f) : (1.0f/ssum);
    #pragma unroll
    for (int g = 0; g < 8; ++g){
      int j0 = (g*64 + lane) * 4;
      float p0 = allm ? inv : sv[g].x * inv;
      float p1 = allm ? inv : sv[g].y * inv;
      float p2 = allm ? inv : sv[g].z * inv;
      float p3 = allm ? inv : sv[g].w * inv;
      if (bf){
        ushort4 u4;
        u4.x = f2b(p0); u4.y = f2b(p1); u4.z = f2b(p2); u4.w = f2b(p3);
        *(ushort4*)((unsigned short*)d_out + OUT0_N + rowm + j0) = u4;
      } else {
        float4 f4; f4.x = p0; f4.y = p1; f4.z = p2; f4.w = p3;
        *(float4*)((float*)d_out + OUT0_N + rowm + j0) = f4;
      }
    }
  }
}

// ---------------- K3: out = LN(attn @ vt^T + q) ----------------
// 128 rows x 256 cols per block, 8 waves (2x4), K=2048 in BK=64 steps.
__global__ __launch_bounds__(512) void k_pv(void* d_out, const unsigned short* vt,
                                            const void* q, const void* gamp,
                                            const void* betp, const int* flags){
  __shared__ unsigned short As[128][72];   // attn tile, pad 8 -> 2-way frag reads
  __shared__ unsigned short Bs[256][72];   // vt tile (d-major, k contiguous)
  __shared__ float psum[4][128];
  __shared__ float psq [4][128];
  __shared__ float gs[256], bs[256];
  __shared__ float mu_s[128], rs_s[128];
  int bf = flags[1];
  int b     = blockIdx.x >> 4;
  int rbase = (blockIdx.x & 15) << 7;
  int t = threadIdx.x;
  int lane = t & 63, wid = t >> 6;
  int wr = wid >> 2, wc = wid & 3;
  int r16 = lane >> 4, c16 = lane & 15;
  if (t < 256){ gs[t] = ldf(gamp, t, bf); bs[t] = ldf(betp, t, bf); }
  const void* attnp = bf ? (const void*)((const unsigned short*)d_out + OUT0_N)
                         : (const void*)((const float*)d_out + OUT0_N);
  const unsigned short* vtb = vt + (long)b * DD * LK;
  long arowbase = (long)(b*LQ + rbase);
  f32x4 acc[4][4];
  #pragma unroll
  for (int i=0;i<4;i++)
    #pragma unroll
    for (int j=0;j<4;j++) acc[i][j] = (f32x4){0.f,0.f,0.f,0.f};

  for (int kt = 0; kt < 32; ++kt){
    __syncthreads();
    int kc = kt * 64;
    #pragma unroll
    for (int s = 0; s < 2; ++s){            // stage A: 128x64
      int u = t + (s << 9);
      int row = u >> 3, part = u & 7;
      s16x8 val = ld8(attnp, (arowbase + row)*(long)LK + kc + part*8, bf);
      *(s16x8*)(&As[row][part*8]) = val;
    }
    #pragma unroll
    for (int s = 0; s < 4; ++s){            // stage B: 256x64 (vt, always bf16)
      int u = t + (s << 9);
      int d = u >> 3, part = u & 7;
      s16x8 val = *(const s16x8*)(vtb + (long)d*LK + kc + part*8);
      *(s16x8*)(&Bs[d][part*8]) = val;
    }
    __syncthreads();
    #pragma unroll
    for (int kg = 0; kg < 2; ++kg){
      int ko = kg*32 + r16*8;
      s16x8 af[4], bq[4];
      #pragma unroll
      for (int mi=0; mi<4; ++mi) af[mi] = *(const s16x8*)(&As[wr*64 + mi*16 + c16][ko]);
      #pragma unroll
      for (int ni=0; ni<4; ++ni) bq[ni] = *(const s16x8*)(&Bs[wc*64 + ni*16 + c16][ko]);
      #pragma unroll
      for (int mi=0; mi<4; ++mi)
        #pragma unroll
        for (int ni=0; ni<4; ++ni)
          acc[mi][ni] = __builtin_amdgcn_mfma_f32_16x16x32_bf16(af[mi], bq[ni], acc[mi][ni], 0,0,0);
    }
  }

  // epilogue: x = acc + q (residual); per-row mean/var across 4 wc-waves; LN
  #pragma unroll
  for (int mi = 0; mi < 4; ++mi){
    #pragma unroll
    for (int reg = 0; reg < 4; ++reg){
      int rl = wr*64 + mi*16 + r16*4 + reg;
      long grow = arowbase + rl;
      float ps = 0.f, pq = 0.f;
      #pragma unroll
      for (int ni = 0; ni < 4; ++ni){
        int col = wc*64 + ni*16 + c16;
        float x = acc[mi][ni][reg] + ldf(q, grow*(long)DD + col, bf);
        acc[mi][ni][reg] = x;
        ps += x; pq += x*x;
      }
      ps += __shfl_xor(ps, 1, 64); pq += __shfl_xor(pq, 1, 64);
      ps += __shfl_xor(ps, 2, 64); pq += __shfl_xor(pq, 2, 64);
      ps += __shfl_xor(ps, 4, 64); pq += __shfl_xor(pq, 4, 64);
      ps += __shfl_xor(ps, 8, 64); pq += __shfl_xor(pq, 8, 64);
      if (c16 == 0){ psum[wc][rl] = ps; psq[wc][rl] = pq; }
    }
  }
  __syncthreads();
  if (t < 128){
    float s  = psum[0][t] + psum[1][t] + psum[2][t] + psum[3][t];
    float s2 = psq [0][t] + psq [1][t] + psq [2][t] + psq [3][t];
    float mu = s * (1.0f/256.0f);
    float var = s2 * (1.0f/256.0f) - mu*mu;
    mu_s[t] = mu;
    rs_s[t] = rsqrtf(var + 1e-5f);
  }
  __syncthreads();
  #pragma unroll
  for (int mi = 0; mi < 4; ++mi){
    #pragma unroll
    for (int ni = 0; ni < 4; ++ni){
      int col = wc*64 + ni*16 + c16;
      float g = gs[col], be = bs[col];
      #pragma unroll
      for (int reg = 0; reg < 4; ++reg){
        int rl = wr*64 + mi*16 + r16*4 + reg;
        float y = (acc[mi][ni][reg] - mu_s[rl]) * rs_s[rl] * g + be;
        long oi = (arowbase + rl)*(long)DD + col;
        if (bf) ((unsigned short*)d_out)[oi] = f2b(y);
        else    ((float*)d_out)[oi] = y;
      }
    }
  }
}

extern "C" void kernel_launch(void* const* d_in, const int* in_sizes, int n_in,
                              void* d_out, int out_size, void* d_ws, size_t ws_size,
                              hipStream_t stream) {
  const void* q    = d_in[0];
  const void* k    = d_in[1];
  const void* v    = d_in[2];
  const void* sh   = d_in[3];
  const void* fc   = d_in[4];
  const void* gam  = d_in[5];
  const void* bet  = d_in[6];
  const void* mask = d_in[7];

  int*            flags = (int*)d_ws;
  float*          sk    = (float*)((char*)d_ws + 1024);            // 16384 f32
  unsigned short* vt    = (unsigned short*)((char*)d_ws + (1<<17)); // 8 MB bf16

  k_detect<<<1,    256, 0, stream>>>(q, mask, flags);
  k_sk    <<<4096, 256, 0, stream>>>(k, sh, sk, flags);
  k_vt    <<<1024, 256, 0, stream>>>(v, fc, vt, flags);
  k_sm    <<<1024, 256, 0, stream>>>(mask, sk, d_out, flags);
  k_pv    <<<128,  512, 0, stream>>>(d_out, vt, q, gam, bet, flags);
}